// Round 2
// baseline (920.498 us; speedup 1.0000x reference)
//
#include <hip/hip_runtime.h>

// ---------------------------------------------------------------------------
// GraphSAGE 3-layer (ClusterGCNNet): per layer
//   agg = mean_{j in N(i)} h_j ;  out = agg @ Wl + h @ Wr + b ; ReLU (layers 0,1)
// Round 2: fix in-place GEMM race (triple-buffer rotation). fp32 baseline.
//   - build CSR (deg -> scan -> fill) once per call
//   - aggregate: 1 wave per node, float4 lanes, no float atomics
//   - fused GEMM: C = Agg@Wl + H@Wr + b (+ReLU), 64x64 tile, BK=32, 4x4 micro
//   - buffers rotate so h_in / agg / h_out are always distinct (no aliasing)
// ---------------------------------------------------------------------------

__global__ void count_deg_kernel(const int* __restrict__ ei, int* __restrict__ deg, int E) {
    int e = blockIdx.x * blockDim.x + threadIdx.x;
    if (e < E) atomicAdd(&deg[ei[E + e]], 1);
}

// single-block exclusive scan of deg[0..n) -> row_ptr[0..n]
__global__ void scan_kernel(const int* __restrict__ deg, int* __restrict__ row_ptr, int n) {
    __shared__ int wsum[16];
    __shared__ int woff[16];
    __shared__ int carry_s;
    const int tid = threadIdx.x, lane = tid & 63, wid = tid >> 6;
    if (tid == 0) { carry_s = 0; row_ptr[0] = 0; }
    __syncthreads();
    for (int base = 0; base < n; base += 1024) {
        int i = base + tid;
        int x = (i < n) ? deg[i] : 0;
        #pragma unroll
        for (int off = 1; off < 64; off <<= 1) {
            int t = __shfl_up(x, off, 64);
            if (lane >= off) x += t;
        }
        if (lane == 63) wsum[wid] = x;
        __syncthreads();
        if (tid == 0) {
            int s = 0;
            #pragma unroll
            for (int w = 0; w < 16; ++w) { woff[w] = s; s += wsum[w]; }
            wsum[0] = s;  // chunk total
        }
        __syncthreads();
        int incl = x + woff[wid] + carry_s;
        if (i < n) row_ptr[i + 1] = incl;
        __syncthreads();
        if (tid == 0) carry_s += wsum[0];
        __syncthreads();
    }
}

__global__ void fill_csr_kernel(const int* __restrict__ ei, int* __restrict__ cursor,
                                int* __restrict__ col, int E) {
    int e = blockIdx.x * blockDim.x + threadIdx.x;
    if (e < E) {
        int s = ei[e];
        int d = ei[E + e];
        int pos = atomicAdd(&cursor[d], 1);
        col[pos] = s;
    }
}

// one wave (64 lanes) per node; lane holds float4 -> 256 features
__global__ __launch_bounds__(256) void aggregate_kernel(
        const float* __restrict__ h, const int* __restrict__ row_ptr,
        const int* __restrict__ col, float* __restrict__ agg, int n) {
    int node = blockIdx.x * 4 + (threadIdx.x >> 6);
    int lane = threadIdx.x & 63;
    if (node >= n) return;
    int start = row_ptr[node], end = row_ptr[node + 1];
    float4 acc = make_float4(0.f, 0.f, 0.f, 0.f);
    for (int e = start; e < end; ++e) {
        int s = col[e];
        float4 v = ((const float4*)(h + (size_t)s * 256))[lane];
        acc.x += v.x; acc.y += v.y; acc.z += v.z; acc.w += v.w;
    }
    int d = end - start;
    float inv = 1.0f / (float)(d > 1 ? d : 1);
    acc.x *= inv; acc.y *= inv; acc.z *= inv; acc.w *= inv;
    ((float4*)(agg + (size_t)node * 256))[lane] = acc;
}

// C[M,N] = Agg[M,256] @ Wl[256,N] + H[M,256] @ Wr[256,N] + b[N]  (+ReLU)
// BM=BN=64, BK=32, 256 threads, 4x4 microtile. A-row loads clamped to M-1 so
// reading directly from x (exactly M rows) is in-bounds; stores guarded.
template<bool RELU>
__global__ __launch_bounds__(256) void gemm_fused_kernel(
        const float* __restrict__ Agg, const float* __restrict__ H,
        const float* __restrict__ Wl, const float* __restrict__ Wr,
        const float* __restrict__ bias, float* __restrict__ C,
        int M, int N) {
    __shared__ float As[32][68];   // [k][row], padded
    __shared__ float Bs[32][68];   // [k][col], padded
    const int tid = threadIdx.x;
    const int tx = tid & 15;       // col group
    const int ty = tid >> 4;       // row group
    const int row0 = blockIdx.x * 64;
    const int col0 = blockIdx.y * 64;

    float acc[4][4];
    #pragma unroll
    for (int r = 0; r < 4; ++r)
        #pragma unroll
        for (int c = 0; c < 4; ++c) acc[r][c] = 0.f;

    #pragma unroll
    for (int s = 0; s < 2; ++s) {
        const float* __restrict__ A = s ? H : Agg;
        const float* __restrict__ B = s ? Wr : Wl;
        for (int k0 = 0; k0 < 256; k0 += 32) {
            // A tile: 64 rows x 32 k (512 float4, 2 per thread), store transposed
            #pragma unroll
            for (int i = 0; i < 2; ++i) {
                int f = tid + i * 256;
                int r = f >> 3;            // row in tile
                int kp = (f & 7) << 2;     // k pos
                int rg = row0 + r; if (rg >= M) rg = M - 1;  // clamp: stay in-bounds
                float4 v = *(const float4*)(A + (size_t)rg * 256 + (k0 + kp));
                As[kp + 0][r] = v.x;
                As[kp + 1][r] = v.y;
                As[kp + 2][r] = v.z;
                As[kp + 3][r] = v.w;
            }
            // B tile: 32 k x 64 n (512 float4, 2 per thread)
            #pragma unroll
            for (int i = 0; i < 2; ++i) {
                int f = tid + i * 256;
                int kk = f >> 4;
                int nf = (f & 15) << 2;
                *(float4*)&Bs[kk][nf] =
                    *(const float4*)(B + (size_t)(k0 + kk) * N + (col0 + nf));
            }
            __syncthreads();
            #pragma unroll
            for (int kk = 0; kk < 32; ++kk) {
                float4 a = *(const float4*)&As[kk][ty << 2];
                float4 b = *(const float4*)&Bs[kk][tx << 2];
                acc[0][0] += a.x * b.x; acc[0][1] += a.x * b.y; acc[0][2] += a.x * b.z; acc[0][3] += a.x * b.w;
                acc[1][0] += a.y * b.x; acc[1][1] += a.y * b.y; acc[1][2] += a.y * b.z; acc[1][3] += a.y * b.w;
                acc[2][0] += a.z * b.x; acc[2][1] += a.z * b.y; acc[2][2] += a.z * b.z; acc[2][3] += a.z * b.w;
                acc[3][0] += a.w * b.x; acc[3][1] += a.w * b.y; acc[3][2] += a.w * b.z; acc[3][3] += a.w * b.w;
            }
            __syncthreads();
        }
    }
    float4 bv = *(const float4*)(bias + col0 + (tx << 2));
    #pragma unroll
    for (int r = 0; r < 4; ++r) {
        int row = row0 + (ty << 2) + r;
        if (row < M) {
            float4 o;
            o.x = acc[r][0] + bv.x;
            o.y = acc[r][1] + bv.y;
            o.z = acc[r][2] + bv.z;
            o.w = acc[r][3] + bv.w;
            if (RELU) {
                o.x = fmaxf(o.x, 0.f); o.y = fmaxf(o.y, 0.f);
                o.z = fmaxf(o.z, 0.f); o.w = fmaxf(o.w, 0.f);
            }
            *(float4*)(C + (size_t)row * N + col0 + (tx << 2)) = o;
        }
    }
}

extern "C" void kernel_launch(void* const* d_in, const int* in_sizes, int n_in,
                              void* d_out, int out_size, void* d_ws, size_t ws_size,
                              hipStream_t stream) {
    const float* x   = (const float*)d_in[0];
    const int*   ei  = (const int*)d_in[1];
    const float* Wl0 = (const float*)d_in[2];
    const float* Wr0 = (const float*)d_in[3];
    const float* b0  = (const float*)d_in[4];
    const float* Wl1 = (const float*)d_in[5];
    const float* Wr1 = (const float*)d_in[6];
    const float* b1  = (const float*)d_in[7];
    const float* Wl2 = (const float*)d_in[8];
    const float* Wr2 = (const float*)d_in[9];
    const float* b2  = (const float*)d_in[10];
    float* out = (float*)d_out;

    const int Nn = in_sizes[0] / 256;       // 50000 nodes
    const int E  = in_sizes[1] / 2;         // 800000 edges
    const int Mpad = ((Nn + 63) / 64) * 64; // 50048

    // workspace layout
    char* ws = (char*)d_ws;
    size_t off = 0;
    auto take = [&](size_t bytes) -> void* {
        void* p = (void*)(ws + off);
        off += (bytes + 255) & ~(size_t)255;
        return p;
    };
    int* deg     = (int*)take((size_t)Nn * 4);
    int* row_ptr = (int*)take((size_t)(Nn + 1) * 4);
    int* cursor  = (int*)take((size_t)Nn * 4);
    int* col     = (int*)take((size_t)E * 4);
    float* bufA  = (float*)take((size_t)Mpad * 256 * 4);
    float* bufB  = (float*)take((size_t)Mpad * 256 * 4);
    float* bufC  = (float*)take((size_t)Mpad * 256 * 4);
    (void)ws_size; (void)n_in; (void)out_size;

    // ---- build CSR (once per call) ----
    hipMemsetAsync(deg, 0, (size_t)Nn * 4, stream);
    count_deg_kernel<<<(E + 255) / 256, 256, 0, stream>>>(ei, deg, E);
    scan_kernel<<<1, 1024, 0, stream>>>(deg, row_ptr, Nn);
    hipMemcpyAsync(cursor, row_ptr, (size_t)Nn * 4, hipMemcpyDeviceToDevice, stream);
    fill_csr_kernel<<<(E + 255) / 256, 256, 0, stream>>>(ei, cursor, col, E);

    const int aggGrid = (Nn + 3) / 4;
    const int gx = (Nn + 63) / 64;

    // ---- layer 0: h_in = x, agg -> bufB, out -> bufC ----
    aggregate_kernel<<<aggGrid, 256, 0, stream>>>(x, row_ptr, col, bufB, Nn);
    gemm_fused_kernel<true><<<dim3(gx, 4), 256, 0, stream>>>(bufB, x, Wl0, Wr0, b0, bufC, Nn, 256);
    // ---- layer 1: h_in = bufC, agg -> bufA, out -> bufB ----
    aggregate_kernel<<<aggGrid, 256, 0, stream>>>(bufC, row_ptr, col, bufA, Nn);
    gemm_fused_kernel<true><<<dim3(gx, 4), 256, 0, stream>>>(bufA, bufC, Wl1, Wr1, b1, bufB, Nn, 256);
    // ---- layer 2: h_in = bufB, agg -> bufA, out -> d_out ----
    aggregate_kernel<<<aggGrid, 256, 0, stream>>>(bufB, row_ptr, col, bufA, Nn);
    gemm_fused_kernel<false><<<dim3(gx, 1), 256, 0, stream>>>(bufA, bufB, Wl2, Wr2, b2, out, Nn, 64);
}

// Round 3
// 426.377 us; speedup vs baseline: 2.1589x; 2.1589x over previous
//
#include <hip/hip_runtime.h>

// ---------------------------------------------------------------------------
// GraphSAGE 3-layer, bf16 pipeline:
//   CSR build (fp32-independent) -> per layer: bf16 mean-aggregate, then
//   MFMA bf16 GEMM  C = [Agg|H] @ [Wl;Wr]^T + b  (+ReLU), fp32 accum.
// Weights pre-transposed+converted once per call: BT[n][k], k=0..511 contiguous.
// ---------------------------------------------------------------------------

typedef short bf16x8 __attribute__((ext_vector_type(8)));
typedef float f32x4 __attribute__((ext_vector_type(4)));

__device__ __forceinline__ unsigned short f2bf(float f) {
    unsigned int b = __float_as_uint(f);
    b += 0x7fffu + ((b >> 16) & 1u);
    return (unsigned short)(b >> 16);
}
__device__ __forceinline__ float bflo(unsigned int u) { return __uint_as_float(u << 16); }
__device__ __forceinline__ float bfhi(unsigned int u) { return __uint_as_float(u & 0xffff0000u); }

__device__ __forceinline__ void gload_lds16(const void* g, void* l) {
    __builtin_amdgcn_global_load_lds(
        (const __attribute__((address_space(1))) void*)g,
        (__attribute__((address_space(3))) void*)l, 16, 0, 0);
}

// ---------------- CSR build ----------------
__global__ void count_deg_kernel(const int* __restrict__ ei, int* __restrict__ deg, int E) {
    int e = blockIdx.x * blockDim.x + threadIdx.x;
    if (e < E) atomicAdd(&deg[ei[E + e]], 1);
}

__global__ void scan_kernel(const int* __restrict__ deg, int* __restrict__ row_ptr, int n) {
    __shared__ int wsum[16];
    __shared__ int woff[16];
    __shared__ int carry_s;
    const int tid = threadIdx.x, lane = tid & 63, wid = tid >> 6;
    if (tid == 0) { carry_s = 0; row_ptr[0] = 0; }
    __syncthreads();
    for (int base = 0; base < n; base += 1024) {
        int i = base + tid;
        int x = (i < n) ? deg[i] : 0;
        #pragma unroll
        for (int off = 1; off < 64; off <<= 1) {
            int t = __shfl_up(x, off, 64);
            if (lane >= off) x += t;
        }
        if (lane == 63) wsum[wid] = x;
        __syncthreads();
        if (tid == 0) {
            int s = 0;
            #pragma unroll
            for (int w = 0; w < 16; ++w) { woff[w] = s; s += wsum[w]; }
            wsum[0] = s;
        }
        __syncthreads();
        int incl = x + woff[wid] + carry_s;
        if (i < n) row_ptr[i + 1] = incl;
        __syncthreads();
        if (tid == 0) carry_s += wsum[0];
        __syncthreads();
    }
}

__global__ void fill_csr_kernel(const int* __restrict__ ei, int* __restrict__ cursor,
                                int* __restrict__ col, int E) {
    int e = blockIdx.x * blockDim.x + threadIdx.x;
    if (e < E) {
        int s = ei[e];
        int d = ei[E + e];
        int pos = atomicAdd(&cursor[d], 1);
        col[pos] = s;
    }
}

// ---------------- converts ----------------
// x fp32 -> bf16, 4 elems/thread
__global__ void cvt_bf16_kernel(const float* __restrict__ x, unsigned short* __restrict__ y, int n4) {
    int i = blockIdx.x * blockDim.x + threadIdx.x;
    if (i < n4) {
        float4 v = ((const float4*)x)[i];
        ushort4 o;
        o.x = f2bf(v.x); o.y = f2bf(v.y); o.z = f2bf(v.z); o.w = f2bf(v.w);
        ((ushort4*)y)[i] = o;
    }
}

// BT[n][k] = (k<256 ? Wl[k][n] : Wr[k-256][n]) as bf16;  N cols, K=512
__global__ void build_bt_kernel(const float* __restrict__ Wl, const float* __restrict__ Wr,
                                unsigned short* __restrict__ BT, int N) {
    int id = blockIdx.x * blockDim.x + threadIdx.x;
    if (id >= N * 512) return;
    int k = id / N;
    int n = id - k * N;
    float v = (k < 256) ? Wl[(size_t)k * N + n] : Wr[(size_t)(k - 256) * N + n];
    BT[(size_t)n * 512 + k] = f2bf(v);
}

// ---------------- aggregation (bf16 in/out, fp32 accum) ----------------
// one wave per node; lane covers 4 features (8B load)
__global__ __launch_bounds__(256) void aggregate_bf16_kernel(
        const unsigned short* __restrict__ h, const int* __restrict__ row_ptr,
        const int* __restrict__ col, unsigned short* __restrict__ agg, int n) {
    int node = blockIdx.x * 4 + (threadIdx.x >> 6);
    int lane = threadIdx.x & 63;
    if (node >= n) return;
    int start = row_ptr[node], end = row_ptr[node + 1];
    float a0 = 0.f, a1 = 0.f, a2 = 0.f, a3 = 0.f;
    int e = start;
    for (; e + 4 <= end; e += 4) {
        int c0 = col[e], c1 = col[e + 1], c2 = col[e + 2], c3 = col[e + 3];
        uint2 v0 = *(const uint2*)(h + (size_t)c0 * 256 + lane * 4);
        uint2 v1 = *(const uint2*)(h + (size_t)c1 * 256 + lane * 4);
        uint2 v2 = *(const uint2*)(h + (size_t)c2 * 256 + lane * 4);
        uint2 v3 = *(const uint2*)(h + (size_t)c3 * 256 + lane * 4);
        a0 += bflo(v0.x) + bflo(v1.x) + bflo(v2.x) + bflo(v3.x);
        a1 += bfhi(v0.x) + bfhi(v1.x) + bfhi(v2.x) + bfhi(v3.x);
        a2 += bflo(v0.y) + bflo(v1.y) + bflo(v2.y) + bflo(v3.y);
        a3 += bfhi(v0.y) + bfhi(v1.y) + bfhi(v2.y) + bfhi(v3.y);
    }
    for (; e < end; ++e) {
        uint2 v = *(const uint2*)(h + (size_t)col[e] * 256 + lane * 4);
        a0 += bflo(v.x); a1 += bfhi(v.x); a2 += bflo(v.y); a3 += bfhi(v.y);
    }
    int d = end - start;
    float inv = 1.0f / (float)(d > 1 ? d : 1);
    ushort4 o;
    o.x = f2bf(a0 * inv); o.y = f2bf(a1 * inv); o.z = f2bf(a2 * inv); o.w = f2bf(a3 * inv);
    *(ushort4*)(agg + (size_t)node * 256 + lane * 4) = o;
}

// ---------------- fused MFMA GEMM ----------------
// C[M,BNblocks*BN] = [Agg|H](M x 512) @ BT^T + bias ; BT is [Ncols][512] bf16.
// BM=128, BN=NT*32, BK=32; 4 waves (2x2), wave tile 64 x (NT*16), 4xNT frags.
template<int NT, bool RELU, bool OUT_BF16>
__global__ __launch_bounds__(256) void gemm_mfma_kernel(
        const unsigned short* __restrict__ Agg, const unsigned short* __restrict__ H,
        const unsigned short* __restrict__ BT, const float* __restrict__ bias,
        void* __restrict__ Cout, int M, int Nc) {
    constexpr int BN = NT * 32;
    __shared__ unsigned short As[128 * 32];
    __shared__ unsigned short Bs[BN * 32];
    const int tid = threadIdx.x;
    const int lane = tid & 63;
    const int wid = tid >> 6;
    const int wr = wid >> 1, wc = wid & 1;
    const int row0 = blockIdx.x * 128;
    const int col0 = blockIdx.y * BN;

    f32x4 acc[4][NT];
    #pragma unroll
    for (int i = 0; i < 4; ++i)
        #pragma unroll
        for (int j = 0; j < NT; ++j) acc[i][j] = (f32x4){0.f, 0.f, 0.f, 0.f};

    const int rA = tid >> 2;           // staging row within tile
    const int kc = (tid & 3) * 8;      // staging k offset (elems)

    for (int ks = 0; ks < 16; ++ks) {
        const unsigned short* Asrc = (ks < 8) ? Agg : H;
        const int kk = (ks & 7) * 32;
        // stage A: 128x32 bf16 (8KB), 2 chunks of 4KB, lane-linear LDS
        #pragma unroll
        for (int i = 0; i < 2; ++i) {
            const unsigned short* g = Asrc + (size_t)(row0 + rA + i * 64) * 256 + kk + kc;
            gload_lds16(g, As + (size_t)i * 2048 + tid * 8);
        }
        // stage B: BNx32 bf16, NT/2 chunks
        #pragma unroll
        for (int i = 0; i < NT / 2; ++i) {
            const unsigned short* g = BT + (size_t)(col0 + rA + i * 64) * 512 + ks * 32 + kc;
            gload_lds16(g, Bs + (size_t)i * 2048 + tid * 8);
        }
        __syncthreads();

        bf16x8 a[4], b[NT];
        #pragma unroll
        for (int tm = 0; tm < 4; ++tm)
            a[tm] = *(const bf16x8*)&As[(wr * 64 + tm * 16 + (lane & 15)) * 32 + (lane >> 4) * 8];
        #pragma unroll
        for (int tn = 0; tn < NT; ++tn)
            b[tn] = *(const bf16x8*)&Bs[(wc * NT * 16 + tn * 16 + (lane & 15)) * 32 + (lane >> 4) * 8];
        #pragma unroll
        for (int tm = 0; tm < 4; ++tm)
            #pragma unroll
            for (int tn = 0; tn < NT; ++tn)
                acc[tm][tn] = __builtin_amdgcn_mfma_f32_16x16x32_bf16(a[tm], b[tn], acc[tm][tn], 0, 0, 0);
        __syncthreads();
    }

    // epilogue: C row = (lane>>4)*4 + r, col = lane&15 (verified m89 layout)
    const int cb = col0 + wc * NT * 16;
    #pragma unroll
    for (int tn = 0; tn < NT; ++tn) {
        int colg = cb + tn * 16 + (lane & 15);
        float bv = bias[colg];
        #pragma unroll
        for (int tm = 0; tm < 4; ++tm) {
            #pragma unroll
            for (int r = 0; r < 4; ++r) {
                int row = row0 + wr * 64 + tm * 16 + (lane >> 4) * 4 + r;
                if (row < M) {
                    float v = acc[tm][tn][r] + bv;
                    if (RELU) v = fmaxf(v, 0.f);
                    if (OUT_BF16)
                        ((unsigned short*)Cout)[(size_t)row * Nc + colg] = f2bf(v);
                    else
                        ((float*)Cout)[(size_t)row * Nc + colg] = v;
                }
            }
        }
    }
}

extern "C" void kernel_launch(void* const* d_in, const int* in_sizes, int n_in,
                              void* d_out, int out_size, void* d_ws, size_t ws_size,
                              hipStream_t stream) {
    const float* x   = (const float*)d_in[0];
    const int*   ei  = (const int*)d_in[1];
    const float* Wl0 = (const float*)d_in[2];
    const float* Wr0 = (const float*)d_in[3];
    const float* b0  = (const float*)d_in[4];
    const float* Wl1 = (const float*)d_in[5];
    const float* Wr1 = (const float*)d_in[6];
    const float* b1  = (const float*)d_in[7];
    const float* Wl2 = (const float*)d_in[8];
    const float* Wr2 = (const float*)d_in[9];
    const float* b2  = (const float*)d_in[10];
    float* out = (float*)d_out;

    const int Nn = in_sizes[0] / 256;          // 50000
    const int E  = in_sizes[1] / 2;            // 800000
    const int Mpad = ((Nn + 127) / 128) * 128; // 50048

    char* ws = (char*)d_ws;
    size_t off = 0;
    auto take = [&](size_t bytes) -> void* {
        void* p = (void*)(ws + off);
        off += (bytes + 255) & ~(size_t)255;
        return p;
    };
    int* deg     = (int*)take((size_t)Nn * 4);
    int* row_ptr = (int*)take((size_t)(Nn + 1) * 4);
    int* cursor  = (int*)take((size_t)Nn * 4);
    int* col     = (int*)take((size_t)E * 4);
    unsigned short* xb  = (unsigned short*)take((size_t)Mpad * 256 * 2);
    unsigned short* h1  = (unsigned short*)take((size_t)Mpad * 256 * 2);
    unsigned short* h2  = (unsigned short*)take((size_t)Mpad * 256 * 2);
    unsigned short* h3  = (unsigned short*)take((size_t)Mpad * 256 * 2);
    unsigned short* BT0 = (unsigned short*)take((size_t)256 * 512 * 2);
    unsigned short* BT1 = (unsigned short*)take((size_t)256 * 512 * 2);
    unsigned short* BT2 = (unsigned short*)take((size_t)64 * 512 * 2);
    (void)ws_size; (void)n_in; (void)out_size;

    // ---- CSR build ----
    hipMemsetAsync(deg, 0, (size_t)Nn * 4, stream);
    count_deg_kernel<<<(E + 255) / 256, 256, 0, stream>>>(ei, deg, E);
    scan_kernel<<<1, 1024, 0, stream>>>(deg, row_ptr, Nn);
    hipMemcpyAsync(cursor, row_ptr, (size_t)Nn * 4, hipMemcpyDeviceToDevice, stream);
    fill_csr_kernel<<<(E + 255) / 256, 256, 0, stream>>>(ei, cursor, col, E);

    // ---- converts ----
    cvt_bf16_kernel<<<(Nn * 64 + 255) / 256, 256, 0, stream>>>(x, xb, Nn * 64);
    build_bt_kernel<<<(256 * 512 + 255) / 256, 256, 0, stream>>>(Wl0, Wr0, BT0, 256);
    build_bt_kernel<<<(256 * 512 + 255) / 256, 256, 0, stream>>>(Wl1, Wr1, BT1, 256);
    build_bt_kernel<<<(64 * 512 + 255) / 256, 256, 0, stream>>>(Wl2, Wr2, BT2, 64);

    const int aggGrid = (Nn + 3) / 4;
    const int gx = Mpad / 128;

    // ---- layer 0 ----
    aggregate_bf16_kernel<<<aggGrid, 256, 0, stream>>>(xb, row_ptr, col, h1, Nn);
    gemm_mfma_kernel<4, true, true><<<dim3(gx, 2), 256, 0, stream>>>(h1, xb, BT0, b0, h2, Nn, 256);
    // ---- layer 1 ----
    aggregate_bf16_kernel<<<aggGrid, 256, 0, stream>>>(h2, row_ptr, col, h1, Nn);
    gemm_mfma_kernel<4, true, true><<<dim3(gx, 2), 256, 0, stream>>>(h1, h2, BT1, b1, h3, Nn, 256);
    // ---- layer 2 ----
    aggregate_bf16_kernel<<<aggGrid, 256, 0, stream>>>(h3, row_ptr, col, h1, Nn);
    gemm_mfma_kernel<2, false, false><<<dim3(gx, 1), 256, 0, stream>>>(h1, h3, BT2, b2, out, Nn, 64);
}

// Round 4
// 373.917 us; speedup vs baseline: 2.4618x; 1.1403x over previous
//
#include <hip/hip_runtime.h>

// ---------------------------------------------------------------------------
// GraphSAGE 3-layer, bf16 pipeline.
// Round 4:
//   - layer 2 reordered: agg(h3)@Wl2 == agg(h3@Wl2)  -> gather 64-dim rows (4x less traffic)
//   - aggregation: 2 edges/wave, 16B/lane loads, unroll-2 (4 gathers in flight)
//   - parallel scan (3 small kernels) instead of single-block serial scan
// ---------------------------------------------------------------------------

typedef short bf16x8 __attribute__((ext_vector_type(8)));
typedef float f32x4 __attribute__((ext_vector_type(4)));

__device__ __forceinline__ unsigned short f2bf(float f) {
    unsigned int b = __float_as_uint(f);
    b += 0x7fffu + ((b >> 16) & 1u);
    return (unsigned short)(b >> 16);
}
__device__ __forceinline__ float bflo(unsigned int u) { return __uint_as_float(u << 16); }
__device__ __forceinline__ float bfhi(unsigned int u) { return __uint_as_float(u & 0xffff0000u); }

__device__ __forceinline__ void gload_lds16(const void* g, void* l) {
    __builtin_amdgcn_global_load_lds(
        (const __attribute__((address_space(1))) void*)g,
        (__attribute__((address_space(3))) void*)l, 16, 0, 0);
}

// ---------------- CSR build ----------------
__global__ void count_deg_kernel(const int* __restrict__ ei, int* __restrict__ deg, int E) {
    int e = blockIdx.x * blockDim.x + threadIdx.x;
    if (e < E) atomicAdd(&deg[ei[E + e]], 1);
}

// per-block inclusive scan of deg -> incl, block sums -> bsum
__global__ __launch_bounds__(1024) void scan1_kernel(
        const int* __restrict__ deg, int* __restrict__ incl, int* __restrict__ bsum, int n) {
    __shared__ int wsum[16];
    __shared__ int woff[16];
    const int tid = threadIdx.x, lane = tid & 63, wid = tid >> 6;
    int i = blockIdx.x * 1024 + tid;
    int x = (i < n) ? deg[i] : 0;
    #pragma unroll
    for (int off = 1; off < 64; off <<= 1) {
        int t = __shfl_up(x, off, 64);
        if (lane >= off) x += t;
    }
    if (lane == 63) wsum[wid] = x;
    __syncthreads();
    if (tid == 0) {
        int s = 0;
        #pragma unroll
        for (int w = 0; w < 16; ++w) { woff[w] = s; s += wsum[w]; }
        bsum[blockIdx.x] = s;
    }
    __syncthreads();
    if (i < n) incl[i] = x + woff[wid];
}

// single wave: exclusive scan of nb (<=64) block sums in place
__global__ void scan2_kernel(int* __restrict__ bsum, int nb) {
    int lane = threadIdx.x;
    int v = (lane < nb) ? bsum[lane] : 0;
    int x = v;
    #pragma unroll
    for (int off = 1; off < 64; off <<= 1) {
        int t = __shfl_up(x, off, 64);
        if (lane >= off) x += t;
    }
    if (lane < nb) bsum[lane] = x - v;   // exclusive
}

__global__ void scan3_kernel(const int* __restrict__ incl, const int* __restrict__ bsum,
                             int* __restrict__ row_ptr, int n) {
    int i = blockIdx.x * blockDim.x + threadIdx.x;
    if (i == 0) row_ptr[0] = 0;
    if (i < n) row_ptr[i + 1] = incl[i] + bsum[i >> 10];
}

__global__ void fill_csr_kernel(const int* __restrict__ ei, int* __restrict__ cursor,
                                int* __restrict__ col, int E) {
    int e = blockIdx.x * blockDim.x + threadIdx.x;
    if (e < E) {
        int s = ei[e];
        int d = ei[E + e];
        int pos = atomicAdd(&cursor[d], 1);
        col[pos] = s;
    }
}

// ---------------- converts ----------------
__global__ void cvt_bf16_kernel(const float* __restrict__ x, unsigned short* __restrict__ y, int n4) {
    int i = blockIdx.x * blockDim.x + threadIdx.x;
    if (i < n4) {
        float4 v = ((const float4*)x)[i];
        ushort4 o;
        o.x = f2bf(v.x); o.y = f2bf(v.y); o.z = f2bf(v.z); o.w = f2bf(v.w);
        ((ushort4*)y)[i] = o;
    }
}

// BT[n][k] = (k<256 ? Wl[k][n] : Wr[k-256][n]) bf16; K=512 concat
__global__ void build_bt_kernel(const float* __restrict__ Wl, const float* __restrict__ Wr,
                                unsigned short* __restrict__ BT, int N) {
    int id = blockIdx.x * blockDim.x + threadIdx.x;
    if (id >= N * 512) return;
    int k = id / N;
    int n = id - k * N;
    float v = (k < 256) ? Wl[(size_t)k * N + n] : Wr[(size_t)(k - 256) * N + n];
    BT[(size_t)n * 512 + k] = f2bf(v);
}

// single W [256][N] -> BT [N][256]
__global__ void build_bt1_kernel(const float* __restrict__ W, unsigned short* __restrict__ BT, int N) {
    int id = blockIdx.x * blockDim.x + threadIdx.x;
    if (id >= N * 256) return;
    int k = id / N;
    int n = id - k * N;
    BT[(size_t)n * 256 + k] = f2bf(W[(size_t)k * N + n]);
}

// ---------------- aggregation, 256-dim (bf16 in/out) ----------------
// one wave per node; 2 edges concurrently (half-waves), 16B/lane, unroll 2
__global__ __launch_bounds__(256) void aggregate256_kernel(
        const unsigned short* __restrict__ h, const int* __restrict__ row_ptr,
        const int* __restrict__ col, unsigned short* __restrict__ agg, int n) {
    int node = blockIdx.x * 4 + (threadIdx.x >> 6);
    int lane = threadIdx.x & 63;
    if (node >= n) return;
    const int start = row_ptr[node], end = row_ptr[node + 1];
    const int half = lane >> 5;
    const int fo = (lane & 31) * 8;     // 8 bf16 per lane
    float a[8] = {0.f, 0.f, 0.f, 0.f, 0.f, 0.f, 0.f, 0.f};
    int eb = start;
    for (; eb + 4 <= end; eb += 4) {
        int e0 = eb + half, e1 = eb + 2 + half;
        uint4 v0 = *(const uint4*)(h + (size_t)col[e0] * 256 + fo);
        uint4 v1 = *(const uint4*)(h + (size_t)col[e1] * 256 + fo);
        a[0] += bflo(v0.x) + bflo(v1.x); a[1] += bfhi(v0.x) + bfhi(v1.x);
        a[2] += bflo(v0.y) + bflo(v1.y); a[3] += bfhi(v0.y) + bfhi(v1.y);
        a[4] += bflo(v0.z) + bflo(v1.z); a[5] += bfhi(v0.z) + bfhi(v1.z);
        a[6] += bflo(v0.w) + bflo(v1.w); a[7] += bfhi(v0.w) + bfhi(v1.w);
    }
    for (; eb < end; eb += 2) {
        int e = eb + half;
        if (e < end) {
            uint4 v = *(const uint4*)(h + (size_t)col[e] * 256 + fo);
            a[0] += bflo(v.x); a[1] += bfhi(v.x);
            a[2] += bflo(v.y); a[3] += bfhi(v.y);
            a[4] += bflo(v.z); a[5] += bfhi(v.z);
            a[6] += bflo(v.w); a[7] += bfhi(v.w);
        }
    }
    #pragma unroll
    for (int i = 0; i < 8; ++i) a[i] += __shfl_xor(a[i], 32, 64);
    int d = end - start;
    float inv = 1.0f / (float)(d > 1 ? d : 1);
    if (lane < 32) {
        ushort4 o0, o1;
        o0.x = f2bf(a[0] * inv); o0.y = f2bf(a[1] * inv);
        o0.z = f2bf(a[2] * inv); o0.w = f2bf(a[3] * inv);
        o1.x = f2bf(a[4] * inv); o1.y = f2bf(a[5] * inv);
        o1.z = f2bf(a[6] * inv); o1.w = f2bf(a[7] * inv);
        *(ushort4*)(agg + (size_t)node * 256 + fo) = o0;
        *(ushort4*)(agg + (size_t)node * 256 + fo + 4) = o1;
    }
}

// ---------------- aggregation, 64-dim (bf16 in, fp32 out) ----------------
// one wave per node; 4 edges concurrently (16-lane groups), 8B/lane, unroll 2
__global__ __launch_bounds__(256) void aggregate64_kernel(
        const unsigned short* __restrict__ p, const int* __restrict__ row_ptr,
        const int* __restrict__ col, float* __restrict__ aggp, int n) {
    int node = blockIdx.x * 4 + (threadIdx.x >> 6);
    int lane = threadIdx.x & 63;
    if (node >= n) return;
    const int start = row_ptr[node], end = row_ptr[node + 1];
    const int g = lane >> 4;            // edge group 0..3
    const int fo = (lane & 15) * 4;     // 4 bf16 per lane
    float a0 = 0.f, a1 = 0.f, a2 = 0.f, a3 = 0.f;
    int eb = start;
    for (; eb + 8 <= end; eb += 8) {
        int e0 = eb + g, e1 = eb + 4 + g;
        uint2 v0 = *(const uint2*)(p + (size_t)col[e0] * 64 + fo);
        uint2 v1 = *(const uint2*)(p + (size_t)col[e1] * 64 + fo);
        a0 += bflo(v0.x) + bflo(v1.x); a1 += bfhi(v0.x) + bfhi(v1.x);
        a2 += bflo(v0.y) + bflo(v1.y); a3 += bfhi(v0.y) + bfhi(v1.y);
    }
    for (; eb < end; eb += 4) {
        int e = eb + g;
        if (e < end) {
            uint2 v = *(const uint2*)(p + (size_t)col[e] * 64 + fo);
            a0 += bflo(v.x); a1 += bfhi(v.x);
            a2 += bflo(v.y); a3 += bfhi(v.y);
        }
    }
    #pragma unroll
    for (int m = 16; m <= 32; m <<= 1) {
        a0 += __shfl_xor(a0, m, 64);
        a1 += __shfl_xor(a1, m, 64);
        a2 += __shfl_xor(a2, m, 64);
        a3 += __shfl_xor(a3, m, 64);
    }
    int d = end - start;
    float inv = 1.0f / (float)(d > 1 ? d : 1);
    if (lane < 16) {
        float4 o = make_float4(a0 * inv, a1 * inv, a2 * inv, a3 * inv);
        *(float4*)(aggp + (size_t)node * 64 + fo) = o;
    }
}

// ---------------- fused MFMA GEMM ----------------
// C = [A0|A1](M x NKS*32) @ BT^T (+bias) (+add) (+relu); BT is [Nc'][NKS*32] bf16.
// A rows are always 256-wide. BM=128, BN=NT*32, BK=32; 4 waves (2x2).
template<int NKS, int NT, bool RELU, bool OUT_BF16, bool HAS_BIAS, bool HAS_ADD>
__global__ __launch_bounds__(256) void gemm_mfma_kernel(
        const unsigned short* __restrict__ A0, const unsigned short* __restrict__ A1,
        const unsigned short* __restrict__ BT, const float* __restrict__ bias,
        const float* __restrict__ add, void* __restrict__ Cout, int M, int Nc) {
    constexpr int BN = NT * 32;
    constexpr int KB = NKS * 32;           // BT row stride (elems)
    __shared__ unsigned short As[128 * 32];
    __shared__ unsigned short Bs[BN * 32];
    const int tid = threadIdx.x;
    const int lane = tid & 63;
    const int wid = tid >> 6;
    const int wr = wid >> 1, wc = wid & 1;
    const int row0 = blockIdx.x * 128;
    const int col0 = blockIdx.y * BN;

    f32x4 acc[4][NT];
    #pragma unroll
    for (int i = 0; i < 4; ++i)
        #pragma unroll
        for (int j = 0; j < NT; ++j) acc[i][j] = (f32x4){0.f, 0.f, 0.f, 0.f};

    const int rA = tid >> 2;
    const int kc = (tid & 3) * 8;

    for (int ks = 0; ks < NKS; ++ks) {
        const unsigned short* Asrc = (NKS == 16) ? (ks < 8 ? A0 : A1) : A0;
        const int ka = (NKS == 16) ? ((ks & 7) * 32) : (ks * 32);
        #pragma unroll
        for (int i = 0; i < 2; ++i) {
            const unsigned short* g = Asrc + (size_t)(row0 + rA + i * 64) * 256 + ka + kc;
            gload_lds16(g, As + (size_t)i * 2048 + tid * 8);
        }
        #pragma unroll
        for (int i = 0; i < NT / 2; ++i) {
            const unsigned short* g = BT + (size_t)(col0 + rA + i * 64) * KB + ks * 32 + kc;
            gload_lds16(g, Bs + (size_t)i * 2048 + tid * 8);
        }
        __syncthreads();

        bf16x8 a[4], b[NT];
        #pragma unroll
        for (int tm = 0; tm < 4; ++tm)
            a[tm] = *(const bf16x8*)&As[(wr * 64 + tm * 16 + (lane & 15)) * 32 + (lane >> 4) * 8];
        #pragma unroll
        for (int tn = 0; tn < NT; ++tn)
            b[tn] = *(const bf16x8*)&Bs[(wc * NT * 16 + tn * 16 + (lane & 15)) * 32 + (lane >> 4) * 8];
        #pragma unroll
        for (int tm = 0; tm < 4; ++tm)
            #pragma unroll
            for (int tn = 0; tn < NT; ++tn)
                acc[tm][tn] = __builtin_amdgcn_mfma_f32_16x16x32_bf16(a[tm], b[tn], acc[tm][tn], 0, 0, 0);
        __syncthreads();
    }

    const int cb = col0 + wc * NT * 16;
    #pragma unroll
    for (int tn = 0; tn < NT; ++tn) {
        int colg = cb + tn * 16 + (lane & 15);
        float bv = HAS_BIAS ? bias[colg] : 0.f;
        #pragma unroll
        for (int tm = 0; tm < 4; ++tm) {
            #pragma unroll
            for (int r = 0; r < 4; ++r) {
                int row = row0 + wr * 64 + tm * 16 + (lane >> 4) * 4 + r;
                if (row < M) {
                    float v = acc[tm][tn][r] + bv;
                    if (HAS_ADD) v += add[(size_t)row * Nc + colg];
                    if (RELU) v = fmaxf(v, 0.f);
                    if (OUT_BF16)
                        ((unsigned short*)Cout)[(size_t)row * Nc + colg] = f2bf(v);
                    else
                        ((float*)Cout)[(size_t)row * Nc + colg] = v;
                }
            }
        }
    }
}

extern "C" void kernel_launch(void* const* d_in, const int* in_sizes, int n_in,
                              void* d_out, int out_size, void* d_ws, size_t ws_size,
                              hipStream_t stream) {
    const float* x   = (const float*)d_in[0];
    const int*   ei  = (const int*)d_in[1];
    const float* Wl0 = (const float*)d_in[2];
    const float* Wr0 = (const float*)d_in[3];
    const float* b0  = (const float*)d_in[4];
    const float* Wl1 = (const float*)d_in[5];
    const float* Wr1 = (const float*)d_in[6];
    const float* b1  = (const float*)d_in[7];
    const float* Wl2 = (const float*)d_in[8];
    const float* Wr2 = (const float*)d_in[9];
    const float* b2  = (const float*)d_in[10];
    float* out = (float*)d_out;

    const int Nn = in_sizes[0] / 256;          // 50000
    const int E  = in_sizes[1] / 2;            // 800000
    const int Mpad = ((Nn + 127) / 128) * 128; // 50048
    const int nb = (Nn + 1023) / 1024;         // scan blocks (49)

    char* ws = (char*)d_ws;
    size_t off = 0;
    auto take = [&](size_t bytes) -> void* {
        void* p = (void*)(ws + off);
        off += (bytes + 255) & ~(size_t)255;
        return p;
    };
    int* deg     = (int*)take((size_t)Nn * 4);
    int* incl    = (int*)take((size_t)Nn * 4);
    int* bsum    = (int*)take((size_t)64 * 4);
    int* row_ptr = (int*)take((size_t)(Nn + 1) * 4);
    int* cursor  = (int*)take((size_t)Nn * 4);
    int* col     = (int*)take((size_t)E * 4);
    unsigned short* xb  = (unsigned short*)take((size_t)Mpad * 256 * 2);
    unsigned short* h1  = (unsigned short*)take((size_t)Mpad * 256 * 2);
    unsigned short* h2  = (unsigned short*)take((size_t)Mpad * 256 * 2);
    unsigned short* h3  = (unsigned short*)take((size_t)Mpad * 256 * 2);
    unsigned short* p2  = (unsigned short*)take((size_t)Mpad * 64 * 2);
    float* aggp = (float*)take((size_t)Mpad * 64 * 4);
    unsigned short* BT0  = (unsigned short*)take((size_t)256 * 512 * 2);
    unsigned short* BT1  = (unsigned short*)take((size_t)256 * 512 * 2);
    unsigned short* BT2l = (unsigned short*)take((size_t)64 * 256 * 2);
    unsigned short* BT2r = (unsigned short*)take((size_t)64 * 256 * 2);
    (void)ws_size; (void)n_in; (void)out_size;

    // ---- CSR build ----
    hipMemsetAsync(deg, 0, (size_t)Nn * 4, stream);
    count_deg_kernel<<<(E + 255) / 256, 256, 0, stream>>>(ei, deg, E);
    scan1_kernel<<<nb, 1024, 0, stream>>>(deg, incl, bsum, Nn);
    scan2_kernel<<<1, 64, 0, stream>>>(bsum, nb);
    scan3_kernel<<<(Nn + 255) / 256, 256, 0, stream>>>(incl, bsum, row_ptr, Nn);
    hipMemcpyAsync(cursor, row_ptr, (size_t)Nn * 4, hipMemcpyDeviceToDevice, stream);
    fill_csr_kernel<<<(E + 255) / 256, 256, 0, stream>>>(ei, cursor, col, E);

    // ---- converts ----
    cvt_bf16_kernel<<<(Nn * 64 + 255) / 256, 256, 0, stream>>>(x, xb, Nn * 64);
    build_bt_kernel<<<(256 * 512 + 255) / 256, 256, 0, stream>>>(Wl0, Wr0, BT0, 256);
    build_bt_kernel<<<(256 * 512 + 255) / 256, 256, 0, stream>>>(Wl1, Wr1, BT1, 256);
    build_bt1_kernel<<<(64 * 256 + 255) / 256, 256, 0, stream>>>(Wl2, BT2l, 64);
    build_bt1_kernel<<<(64 * 256 + 255) / 256, 256, 0, stream>>>(Wr2, BT2r, 64);

    const int aggGrid = (Nn + 3) / 4;
    const int gx = Mpad / 128;

    // ---- layer 0 ----
    aggregate256_kernel<<<aggGrid, 256, 0, stream>>>(xb, row_ptr, col, h1, Nn);
    gemm_mfma_kernel<16, 4, true, true, true, false><<<dim3(gx, 2), 256, 0, stream>>>(
        h1, xb, BT0, b0, nullptr, h2, Nn, 256);
    // ---- layer 1 ----
    aggregate256_kernel<<<aggGrid, 256, 0, stream>>>(h2, row_ptr, col, h1, Nn);
    gemm_mfma_kernel<16, 4, true, true, true, false><<<dim3(gx, 2), 256, 0, stream>>>(
        h1, h2, BT1, b1, nullptr, h3, Nn, 256);
    // ---- layer 2: agg(h3)@Wl2 == agg(h3@Wl2) ----
    gemm_mfma_kernel<8, 2, false, true, false, false><<<dim3(gx, 1), 256, 0, stream>>>(
        h3, nullptr, BT2l, nullptr, nullptr, p2, Nn, 64);
    aggregate64_kernel<<<aggGrid, 256, 0, stream>>>(p2, row_ptr, col, aggp, Nn);
    gemm_mfma_kernel<8, 2, false, false, true, true><<<dim3(gx, 1), 256, 0, stream>>>(
        h3, nullptr, BT2r, b2, aggp, out, Nn, 64);
}